// Round 8
// baseline (298.666 us; speedup 1.0000x reference)
//
#include <hip/hip_runtime.h>
#include <hip/hip_bf16.h>

#define BB 4
#define NN 32768
#define KKN 16          // neighbors per node
#define IN_DIM 32
#define HID 64
#define OUT_DIM 32
#define KH 64
#define WS 88           // LDS row stride in bf16 elems (176 B, 16B-aligned)
#define TOT (BB * NN)   // 131072 = 2^17
#define NWAVES 8192     // grid 2048 blocks x 4 waves
#define GTAB_N 4096     // gelu table entries, step 1/128 over [-16,16)

typedef __bf16 bf16;
typedef float f32x4 __attribute__((ext_vector_type(4)));
typedef bf16 bf16x8 __attribute__((ext_vector_type(8)));
typedef bf16 bf16x4 __attribute__((ext_vector_type(4)));

// gelu, tanh formulation, exp2-native (point kernel + table build use exact erf instead)
__device__ __forceinline__ float gelu_f(float x) {
    float x2 = x * x;
    float t  = x * fmaf(0.10294358f, x2, 2.3022082f);
    float E  = __builtin_amdgcn_exp2f(t);
    float r  = __builtin_amdgcn_rcpf(E + 1.0f);
    return fmaf(-x, r, x);   // x - x/(e^{2t}+1)
}

// DPP add: v += lane-permuted v (within 16-lane row). CTRL must be an immediate:
// 0xB1=quad_perm xor1, 0x4E=quad_perm xor2, 0x124=row_ror:4, 0x128=row_ror:8.
template <int CTRL>
__device__ __forceinline__ float dppadd(float v) {
    union { float f; int i; } u, r;
    u.f = v;
    r.i = __builtin_amdgcn_update_dpp(0, u.i, CTRL, 0xf, 0xf, true);
    return v + r.f;
}
__device__ __forceinline__ float rowsum16(float v) {
    v = dppadd<0xB1>(v);    // quad xor 1
    v = dppadd<0x4E>(v);    // quad xor 2
    v = dppadd<0x124>(v);   // row rotate 4
    v = dppadd<0x128>(v);   // row rotate 8
    return v;
}

// ---------------- Kernel A: point MLP via MFMA (persistent) ----------------
__global__ __launch_bounds__(256) void point_mlp_kernel(
    const float* __restrict__ inp, const float* __restrict__ Wp1,
    const float* __restrict__ bp1, const float* __restrict__ Wp2,
    const float* __restrict__ bp2, bf16* __restrict__ xbf)
{
    __shared__ __align__(16) bf16 hb[4][16 * WS];
    const int tid = threadIdx.x, w = tid >> 6, lane = tid & 63;
    const int q = lane >> 4, nl = lane & 15;

    bf16x8 w1f[4];
    #pragma unroll
    for (int nb = 0; nb < 4; nb++)
        #pragma unroll
        for (int j = 0; j < 8; j++)
            w1f[nb][j] = (bf16)Wp1[(q * 8 + j) * HID + nb * 16 + nl];
    bf16x8 w2f[2][2];        // rows pre-permuted by p_inv(k) = (k&3)*16 + k/4
    #pragma unroll
    for (int nb = 0; nb < 2; nb++)
        #pragma unroll
        for (int c = 0; c < 2; c++)
            #pragma unroll
            for (int j = 0; j < 8; j++) {
                int k = c * 32 + q * 8 + j, kp = ((k & 3) << 4) | (k >> 2);
                w2f[nb][c][j] = (bf16)Wp2[kp * OUT_DIM + nb * 16 + nl];
            }
    float b1v[4], b2v[2];
    #pragma unroll
    for (int nb = 0; nb < 4; nb++) b1v[nb] = bp1[nb * 16 + nl];
    b2v[0] = bp2[nl]; b2v[1] = bp2[16 + nl];

    const int gw = blockIdx.x * 4 + w;
    const int nw = gridDim.x * 4;

    for (int t = gw; t < TOT / 16; t += nw) {
        const int R = t * 16;
        const float* ap = inp + (size_t)(R + nl) * IN_DIM + q * 8;
        float4 av0 = *(const float4*)ap, av1 = *(const float4*)(ap + 4);
        bf16x8 af;
        af[0] = (bf16)av0.x; af[1] = (bf16)av0.y; af[2] = (bf16)av0.z; af[3] = (bf16)av0.w;
        af[4] = (bf16)av1.x; af[5] = (bf16)av1.y; af[6] = (bf16)av1.z; af[7] = (bf16)av1.w;

        f32x4 acc[4];
        #pragma unroll
        for (int nb = 0; nb < 4; nb++)
            acc[nb] = (f32x4){b1v[nb], b1v[nb], b1v[nb], b1v[nb]};
        #pragma unroll
        for (int nb = 0; nb < 4; nb++)
            acc[nb] = __builtin_amdgcn_mfma_f32_16x16x32_bf16(af, w1f[nb], acc[nb], 0, 0, 0);

        #pragma unroll
        for (int r = 0; r < 4; r++) {
            bf16x4 hv;
            #pragma unroll
            for (int nb = 0; nb < 4; nb++) hv[nb] = (bf16)gelu_f(acc[nb][r]);
            *(bf16x4*)&hb[w][(q * 4 + r) * WS + nl * 4] = hv;
        }
        bf16x8 a0 = *(const bf16x8*)&hb[w][nl * WS + q * 8];
        bf16x8 a1 = *(const bf16x8*)&hb[w][nl * WS + 32 + q * 8];
        f32x4 a2[2];
        #pragma unroll
        for (int nb = 0; nb < 2; nb++) {
            a2[nb] = (f32x4){b2v[nb], b2v[nb], b2v[nb], b2v[nb]};
            a2[nb] = __builtin_amdgcn_mfma_f32_16x16x32_bf16(a0, w2f[nb][0], a2[nb], 0, 0, 0);
            a2[nb] = __builtin_amdgcn_mfma_f32_16x16x32_bf16(a1, w2f[nb][1], a2[nb], 0, 0, 0);
        }
        #pragma unroll
        for (int r = 0; r < 4; r++)
            #pragma unroll
            for (int nb = 0; nb < 2; nb++)
                xbf[(size_t)(R + q * 4 + r) * OUT_DIM + nb * 16 + nl] = (bf16)a2[nb][r];
    }
}

// ---------------- Kernel B: edge MLP, 2 nodes/iter + LDS gelu LUT + LDS-resident W2/W3 frags ----------------
__global__ __launch_bounds__(256, 3) void gnn_edge_kernel(
    const bf16*  __restrict__ xbf,
    const float* __restrict__ igrid, const float* __restrict__ ogrid,
    const int*   __restrict__ nbi,
    const float* __restrict__ Wk1, const float* __restrict__ bk1,
    const float* __restrict__ Wk2, const float* __restrict__ bk2,
    const float* __restrict__ Wk3, const float* __restrict__ bk3,
    const float* __restrict__ gma, const float* __restrict__ bta,
    float* __restrict__ out)
{
    __shared__ __align__(16) bf16 tile[8][16 * WS];   // 2 tiles per wave        (22.0 KB)
    __shared__ __align__(16) bf16 gtab[GTAB_N];       // gelu LUT [-16,16)/128   ( 8.0 KB)
    __shared__ __align__(16) bf16 w2s[8 * 64 * 8];    // W2 B-frags, [frag][lane][8] (8 KB)
    __shared__ __align__(16) bf16 w3s[4 * 64 * 8];    // W3 B-frags              ( 4.0 KB)

    const int tid = threadIdx.x, w = tid >> 6, lane = tid & 63;
    const int q = lane >> 4, nl = lane & 15;
    bf16* __restrict__ TA = tile[w * 2];
    bf16* __restrict__ TB = tile[w * 2 + 1];

    // ---- build gelu table (exact erf), once per block ----
    for (int i = tid; i < GTAB_N; i += 256) {
        float x = (float)i * 0.0078125f - 16.0f;
        gtab[i] = (bf16)(0.5f * x * (1.0f + erff(x * 0.70710678f)));
    }
    // ---- build W2/W3 B-frag tables in LDS (shared by all waves; rows pre-permuted by p_inv) ----
    // frag f = nb*2+c; entry [f*64 + l] holds the 8 bf16 of lane l's frag (16B).
    for (int idx = tid; idx < 8 * 64; idx += 256) {
        int f = idx >> 6, l = idx & 63;
        int fnb = f >> 1, fc = f & 1, fq = l >> 4, fnl = l & 15;
        bf16x8 v;
        #pragma unroll
        for (int j = 0; j < 8; j++) {
            int k = fc * 32 + fq * 8 + j, kp = ((k & 3) << 4) | (k >> 2);
            v[j] = (bf16)Wk2[kp * KH + fnb * 16 + fnl];
        }
        *(bf16x8*)&w2s[idx * 8] = v;
        if (f < 4) {
            bf16x8 v3;
            #pragma unroll
            for (int j = 0; j < 8; j++) {
                int k = fc * 32 + fq * 8 + j, kp = ((k & 3) << 4) | (k >> 2);
                v3[j] = (bf16)Wk3[kp * OUT_DIM + fnb * 16 + fnl];
            }
            *(bf16x8*)&w3s[idx * 8] = v3;
        }
    }

    // ---- W1 B-frags stay in registers (32 VGPR) ----
    bf16x8 w1f[4][2];
    #pragma unroll
    for (int nb = 0; nb < 4; nb++) {
        #pragma unroll
        for (int j = 0; j < 8; j++) {
            w1f[nb][0][j] = (bf16)Wk1[(4 + q * 8 + j) * KH + nb * 16 + nl];
            float v1 = 0.0f;
            if (j < 4 && q == 0) v1 = Wk1[j * KH + nb * 16 + nl];
            w1f[nb][1][j] = (bf16)v1;
        }
    }

    float b1v[4], b2v[4], b3v[2];
    #pragma unroll
    for (int nb = 0; nb < 4; nb++) { b1v[nb] = bk1[nb * 16 + nl]; b2v[nb] = bk2[nb * 16 + nl]; }
    b3v[0] = bk3[nl]; b3v[1] = bk3[16 + nl];
    const float g0 = gma[nl], g1 = gma[16 + nl], be0 = bta[nl], be1 = bta[16 + nl];

    const int gw = blockIdx.x * 4 + w;
    const int e = lane >> 2, part = lane & 3;

    // zero both tiles fully once (cols 36..63 stay zero forever; 0..35 rewritten per task)
    {
        const bf16x8 zf = {(bf16)0.f,(bf16)0.f,(bf16)0.f,(bf16)0.f,(bf16)0.f,(bf16)0.f,(bf16)0.f,(bf16)0.f};
        for (int i = lane * 8; i < 16 * WS; i += 64 * 8) { *(bf16x8*)&TA[i] = zf; *(bf16x8*)&TB[i] = zf; }
    }
    __syncthreads();   // tables ready (one-time barrier)

    // gelu lookup: idx = round(x*128) + 2048, clamped
    #define GLUT(x) gtab[(unsigned)fminf(fmaxf(fmaf((x), 128.0f, 2048.5f), 0.0f), 4095.0f)]

    // ---- prologue prefetch (pair 0) ----
    int tA = gw, tB = gw + NWAVES;
    int nA = nbi[(tA & (NN - 1)) * KKN + e];
    int nB = nbi[(tB & (NN - 1)) * KKN + e];
    uint4 fyA = ((const uint4*)(xbf + ((size_t)((tA >> 15) * NN + nA)) * OUT_DIM))[part];
    uint4 fyB = ((const uint4*)(xbf + ((size_t)((tB >> 15) * NN + nB)) * OUT_DIM))[part];
    float2 ipA, opA, ipB, opB;
    if (part == 0) {
        ipA = ((const float2*)igrid)[nA]; opA = ((const float2*)ogrid)[tA & (NN - 1)];
        ipB = ((const float2*)igrid)[nB]; opB = ((const float2*)ogrid)[tB & (NN - 1)];
    }
    bf16 xA0 = xbf[(size_t)tA * OUT_DIM + nl],      xA1 = xbf[(size_t)tA * OUT_DIM + 16 + nl];
    bf16 xB0 = xbf[(size_t)tB * OUT_DIM + nl],      xB1 = xbf[(size_t)tB * OUT_DIM + 16 + nl];

    #pragma unroll 1
    for (int it = 0; it < TOT / (2 * NWAVES); ++it) {
        // ---- commit prefetched gathers ----
        *(uint4*)&TA[e * WS + part * 8] = fyA;
        *(uint4*)&TB[e * WS + part * 8] = fyB;
        if (part == 0) {
            bf16x4 pA = {(bf16)ipA.x, (bf16)ipA.y, (bf16)opA.x, (bf16)opA.y};
            bf16x4 pB = {(bf16)ipB.x, (bf16)ipB.y, (bf16)opB.x, (bf16)opB.y};
            *(bf16x4*)&TA[e * WS + 32] = pA;
            *(bf16x4*)&TB[e * WS + 32] = pB;
        }
        const float rA0 = (float)xA0, rA1 = (float)xA1, rB0 = (float)xB0, rB1 = (float)xB1;

        // ---- next pair indices (wraparound, always valid) ----
        const int tA2 = (tA + 2 * NWAVES) & (TOT - 1);
        const int tB2 = tA2 + NWAVES;
        const int nA2 = nbi[(tA2 & (NN - 1)) * KKN + e];
        const int nB2 = nbi[(tB2 & (NN - 1)) * KKN + e];

        // ---- layer 1 (A and B interleaved) ----
        bf16x8 aA0 = *(const bf16x8*)&TA[nl * WS + q * 8];
        bf16x8 aA1 = *(const bf16x8*)&TA[nl * WS + 32 + q * 8];
        bf16x8 aB0 = *(const bf16x8*)&TB[nl * WS + q * 8];
        bf16x8 aB1 = *(const bf16x8*)&TB[nl * WS + 32 + q * 8];
        f32x4 cA[4], cB[4];
        #pragma unroll
        for (int nb = 0; nb < 4; nb++) {
            cA[nb] = (f32x4){b1v[nb], b1v[nb], b1v[nb], b1v[nb]};
            cB[nb] = (f32x4){b1v[nb], b1v[nb], b1v[nb], b1v[nb]};
        }
        #pragma unroll
        for (int nb = 0; nb < 4; nb++) {
            cA[nb] = __builtin_amdgcn_mfma_f32_16x16x32_bf16(aA0, w1f[nb][0], cA[nb], 0, 0, 0);
            cB[nb] = __builtin_amdgcn_mfma_f32_16x16x32_bf16(aB0, w1f[nb][0], cB[nb], 0, 0, 0);
            cA[nb] = __builtin_amdgcn_mfma_f32_16x16x32_bf16(aA1, w1f[nb][1], cA[nb], 0, 0, 0);
            cB[nb] = __builtin_amdgcn_mfma_f32_16x16x32_bf16(aB1, w1f[nb][1], cB[nb], 0, 0, 0);
        }
        #pragma unroll
        for (int r = 0; r < 4; r++) {
            bf16x4 hA, hB;
            #pragma unroll
            for (int nb = 0; nb < 4; nb++) {
                hA[nb] = GLUT(cA[nb][r]);
                hB[nb] = GLUT(cB[nb][r]);
            }
            *(bf16x4*)&TA[(q * 4 + r) * WS + nl * 4] = hA;
            *(bf16x4*)&TB[(q * 4 + r) * WS + nl * 4] = hB;
        }

        // ---- issue next pair's gathers (overlap layers 2-3) ----
        uint4 fyA2 = ((const uint4*)(xbf + ((size_t)((tA2 >> 15) * NN + nA2)) * OUT_DIM))[part];
        uint4 fyB2 = ((const uint4*)(xbf + ((size_t)((tB2 >> 15) * NN + nB2)) * OUT_DIM))[part];
        float2 ipA2, opA2, ipB2, opB2;
        if (part == 0) {
            ipA2 = ((const float2*)igrid)[nA2]; opA2 = ((const float2*)ogrid)[tA2 & (NN - 1)];
            ipB2 = ((const float2*)igrid)[nB2]; opB2 = ((const float2*)ogrid)[tB2 & (NN - 1)];
        }
        bf16 xA0n = xbf[(size_t)tA2 * OUT_DIM + nl],  xA1n = xbf[(size_t)tA2 * OUT_DIM + 16 + nl];
        bf16 xB0n = xbf[(size_t)tB2 * OUT_DIM + nl],  xB1n = xbf[(size_t)tB2 * OUT_DIM + 16 + nl];

        // ---- layer 2 (W2 frags streamed from LDS) ----
        aA0 = *(const bf16x8*)&TA[nl * WS + q * 8];
        aA1 = *(const bf16x8*)&TA[nl * WS + 32 + q * 8];
        aB0 = *(const bf16x8*)&TB[nl * WS + q * 8];
        aB1 = *(const bf16x8*)&TB[nl * WS + 32 + q * 8];
        #pragma unroll
        for (int nb = 0; nb < 4; nb++) {
            cA[nb] = (f32x4){b2v[nb], b2v[nb], b2v[nb], b2v[nb]};
            cB[nb] = (f32x4){b2v[nb], b2v[nb], b2v[nb], b2v[nb]};
        }
        #pragma unroll
        for (int nb = 0; nb < 4; nb++) {
            bf16x8 wf0 = *(const bf16x8*)&w2s[((nb * 2 + 0) * 64 + lane) * 8];
            bf16x8 wf1 = *(const bf16x8*)&w2s[((nb * 2 + 1) * 64 + lane) * 8];
            cA[nb] = __builtin_amdgcn_mfma_f32_16x16x32_bf16(aA0, wf0, cA[nb], 0, 0, 0);
            cB[nb] = __builtin_amdgcn_mfma_f32_16x16x32_bf16(aB0, wf0, cB[nb], 0, 0, 0);
            cA[nb] = __builtin_amdgcn_mfma_f32_16x16x32_bf16(aA1, wf1, cA[nb], 0, 0, 0);
            cB[nb] = __builtin_amdgcn_mfma_f32_16x16x32_bf16(aB1, wf1, cB[nb], 0, 0, 0);
        }
        #pragma unroll
        for (int r = 0; r < 4; r++) {
            bf16x4 hA, hB;
            #pragma unroll
            for (int nb = 0; nb < 4; nb++) {
                hA[nb] = GLUT(cA[nb][r]);
                hB[nb] = GLUT(cB[nb][r]);
            }
            *(bf16x4*)&TA[(q * 4 + r) * WS + nl * 4] = hA;
            *(bf16x4*)&TB[(q * 4 + r) * WS + nl * 4] = hB;
        }

        // ---- layer 3 (W3 frags streamed from LDS) ----
        aA0 = *(const bf16x8*)&TA[nl * WS + q * 8];
        aA1 = *(const bf16x8*)&TA[nl * WS + 32 + q * 8];
        aB0 = *(const bf16x8*)&TB[nl * WS + q * 8];
        aB1 = *(const bf16x8*)&TB[nl * WS + 32 + q * 8];
        f32x4 dA[2], dB[2];
        #pragma unroll
        for (int nb = 0; nb < 2; nb++) {
            bf16x8 wf0 = *(const bf16x8*)&w3s[((nb * 2 + 0) * 64 + lane) * 8];
            bf16x8 wf1 = *(const bf16x8*)&w3s[((nb * 2 + 1) * 64 + lane) * 8];
            dA[nb] = (f32x4){0.f, 0.f, 0.f, 0.f};
            dB[nb] = (f32x4){0.f, 0.f, 0.f, 0.f};
            dA[nb] = __builtin_amdgcn_mfma_f32_16x16x32_bf16(aA0, wf0, dA[nb], 0, 0, 0);
            dB[nb] = __builtin_amdgcn_mfma_f32_16x16x32_bf16(aB0, wf0, dB[nb], 0, 0, 0);
            dA[nb] = __builtin_amdgcn_mfma_f32_16x16x32_bf16(aA1, wf1, dA[nb], 0, 0, 0);
            dB[nb] = __builtin_amdgcn_mfma_f32_16x16x32_bf16(aB1, wf1, dB[nb], 0, 0, 0);
        }

        // ---- epilogues: mean over 16 edges + bias + residual, LN over 32 (DPP row sums) ----
        {
            float s0 = dA[0][0] + dA[0][1] + dA[0][2] + dA[0][3];
            float s1 = dA[1][0] + dA[1][1] + dA[1][2] + dA[1][3];
            float u0 = dB[0][0] + dB[0][1] + dB[0][2] + dB[0][3];
            float u1 = dB[1][0] + dB[1][1] + dB[1][2] + dB[1][3];
            s0 += __shfl_xor(s0, 16, 64); s0 += __shfl_xor(s0, 32, 64);
            s1 += __shfl_xor(s1, 16, 64); s1 += __shfl_xor(s1, 32, 64);
            u0 += __shfl_xor(u0, 16, 64); u0 += __shfl_xor(u0, 32, 64);
            u1 += __shfl_xor(u1, 16, 64); u1 += __shfl_xor(u1, 32, 64);

            float oA0 = s0 * 0.0625f + b3v[0] + rA0;
            float oA1 = s1 * 0.0625f + b3v[1] + rA1;
            float oB0 = u0 * 0.0625f + b3v[0] + rB0;
            float oB1 = u1 * 0.0625f + b3v[1] + rB1;

            // LN mean/var: sums over the 16-lane nl dimension -> DPP (VALU pipe, no LDS)
            float mA = rowsum16(oA0 + oA1) * (1.0f / 32.0f);
            float mB = rowsum16(oB0 + oB1) * (1.0f / 32.0f);
            float dA0 = oA0 - mA, dA1 = oA1 - mA, dB0 = oB0 - mB, dB1 = oB1 - mB;
            float vA = rowsum16(dA0 * dA0 + dA1 * dA1) * (1.0f / 32.0f);
            float vB = rowsum16(dB0 * dB0 + dB1 * dB1) * (1.0f / 32.0f);
            float rsA = rsqrtf(vA + 1e-5f);
            float rsB = rsqrtf(vB + 1e-5f);

            if (q == 0) {
                float* oa = out + (size_t)tA * OUT_DIM;
                float* ob = out + (size_t)tB * OUT_DIM;
                oa[nl]      = fmaf(dA0 * rsA, g0, be0);
                oa[16 + nl] = fmaf(dA1 * rsA, g1, be1);
                ob[nl]      = fmaf(dB0 * rsB, g0, be0);
                ob[16 + nl] = fmaf(dB1 * rsB, g1, be1);
            }
        }

        // ---- rotate prefetch state ----
        tA = tA2; tB = tB2;
        fyA = fyA2; fyB = fyB2;
        ipA = ipA2; opA = opA2; ipB = ipB2; opB = opB2;
        xA0 = xA0n; xA1 = xA1n; xB0 = xB0n; xB1 = xB1n;
    }
    #undef GLUT
}

extern "C" void kernel_launch(void* const* d_in, const int* in_sizes, int n_in,
                              void* d_out, int out_size, void* d_ws, size_t ws_size,
                              hipStream_t stream) {
    const float* inp   = (const float*)d_in[0];
    const float* igrid = (const float*)d_in[1];
    const float* ogrid = (const float*)d_in[2];
    const int*   nbi   = (const int*)d_in[3];
    const float* Wp1   = (const float*)d_in[4];
    const float* bp1   = (const float*)d_in[5];
    const float* Wp2   = (const float*)d_in[6];
    const float* bp2   = (const float*)d_in[7];
    const float* Wk1   = (const float*)d_in[8];
    const float* bk1   = (const float*)d_in[9];
    const float* Wk2   = (const float*)d_in[10];
    const float* bk2   = (const float*)d_in[11];
    const float* Wk3   = (const float*)d_in[12];
    const float* bk3   = (const float*)d_in[13];
    const float* gma   = (const float*)d_in[14];
    const float* bta   = (const float*)d_in[15];
    float* out = (float*)d_out;
    bf16* xbf = (bf16*)d_ws;   // B*N*32 bf16 = 8 MB

    point_mlp_kernel<<<1024, 256, 0, stream>>>(inp, Wp1, bp1, Wp2, bp2, xbf);
    gnn_edge_kernel<<<2048, 256, 0, stream>>>(xbf, igrid, ogrid, nbi,
                                              Wk1, bk1, Wk2, bk2, Wk3, bk3,
                                              gma, bta, out);
}

// Round 9
// 212.654 us; speedup vs baseline: 1.4045x; 1.4045x over previous
//
#include <hip/hip_runtime.h>
#include <hip/hip_bf16.h>

#define BB 4
#define NN 32768
#define KKN 16          // neighbors per node
#define IN_DIM 32
#define HID 64
#define OUT_DIM 32
#define KH 64
#define WS 88           // LDS row stride in bf16 elems (176 B, 16B-aligned)
#define TOT (BB * NN)   // 131072 = 2^17
#define NWAVES 8192     // grid 2048 blocks x 4 waves
#define GTAB_N 4096     // gelu table entries, step 1/128 over [-16,16)

typedef __bf16 bf16;
typedef float f32x4 __attribute__((ext_vector_type(4)));
typedef bf16 bf16x8 __attribute__((ext_vector_type(8)));
typedef bf16 bf16x4 __attribute__((ext_vector_type(4)));

// gelu, tanh formulation, exp2-native: arg = x*(2.3022082 + 0.10294358 x^2); 7 VALU (2 quarter-rate)
__device__ __forceinline__ float gelu_f(float x) {
    float x2 = x * x;
    float t  = x * fmaf(0.10294358f, x2, 2.3022082f);
    float E  = __builtin_amdgcn_exp2f(t);
    float r  = __builtin_amdgcn_rcpf(E + 1.0f);
    return fmaf(-x, r, x);   // x - x/(e^{2t}+1)
}

// DPP add: v += lane-permuted v (within 16-lane row). CTRL immediate:
// 0xB1=quad_perm xor1, 0x4E=quad_perm xor2, 0x124=row_ror:4, 0x128=row_ror:8.
template <int CTRL>
__device__ __forceinline__ float dppadd(float v) {
    union { float f; int i; } u, r;
    u.f = v;
    r.i = __builtin_amdgcn_update_dpp(0, u.i, CTRL, 0xf, 0xf, true);
    return v + r.f;
}
__device__ __forceinline__ float rowsum16(float v) {
    v = dppadd<0xB1>(v);    // quad xor 1
    v = dppadd<0x4E>(v);    // quad xor 2
    v = dppadd<0x124>(v);   // row rotate 4
    v = dppadd<0x128>(v);   // row rotate 8
    return v;
}

// ---------------- Kernel A: point MLP via MFMA (persistent) ----------------
__global__ __launch_bounds__(256) void point_mlp_kernel(
    const float* __restrict__ inp, const float* __restrict__ Wp1,
    const float* __restrict__ bp1, const float* __restrict__ Wp2,
    const float* __restrict__ bp2, bf16* __restrict__ xbf)
{
    __shared__ __align__(16) bf16 hb[4][16 * WS];
    const int tid = threadIdx.x, w = tid >> 6, lane = tid & 63;
    const int q = lane >> 4, nl = lane & 15;

    bf16x8 w1f[4];
    #pragma unroll
    for (int nb = 0; nb < 4; nb++)
        #pragma unroll
        for (int j = 0; j < 8; j++)
            w1f[nb][j] = (bf16)Wp1[(q * 8 + j) * HID + nb * 16 + nl];
    bf16x8 w2f[2][2];        // rows pre-permuted by p_inv(k) = (k&3)*16 + k/4
    #pragma unroll
    for (int nb = 0; nb < 2; nb++)
        #pragma unroll
        for (int c = 0; c < 2; c++)
            #pragma unroll
            for (int j = 0; j < 8; j++) {
                int k = c * 32 + q * 8 + j, kp = ((k & 3) << 4) | (k >> 2);
                w2f[nb][c][j] = (bf16)Wp2[kp * OUT_DIM + nb * 16 + nl];
            }
    float b1v[4], b2v[2];
    #pragma unroll
    for (int nb = 0; nb < 4; nb++) b1v[nb] = bp1[nb * 16 + nl];
    b2v[0] = bp2[nl]; b2v[1] = bp2[16 + nl];

    const int gw = blockIdx.x * 4 + w;
    const int nw = gridDim.x * 4;

    for (int t = gw; t < TOT / 16; t += nw) {
        const int R = t * 16;
        const float* ap = inp + (size_t)(R + nl) * IN_DIM + q * 8;
        float4 av0 = *(const float4*)ap, av1 = *(const float4*)(ap + 4);
        bf16x8 af;
        af[0] = (bf16)av0.x; af[1] = (bf16)av0.y; af[2] = (bf16)av0.z; af[3] = (bf16)av0.w;
        af[4] = (bf16)av1.x; af[5] = (bf16)av1.y; af[6] = (bf16)av1.z; af[7] = (bf16)av1.w;

        f32x4 acc[4];
        #pragma unroll
        for (int nb = 0; nb < 4; nb++)
            acc[nb] = (f32x4){b1v[nb], b1v[nb], b1v[nb], b1v[nb]};
        #pragma unroll
        for (int nb = 0; nb < 4; nb++)
            acc[nb] = __builtin_amdgcn_mfma_f32_16x16x32_bf16(af, w1f[nb], acc[nb], 0, 0, 0);

        #pragma unroll
        for (int r = 0; r < 4; r++) {
            bf16x4 hv;
            #pragma unroll
            for (int nb = 0; nb < 4; nb++) hv[nb] = (bf16)gelu_f(acc[nb][r]);
            *(bf16x4*)&hb[w][(q * 4 + r) * WS + nl * 4] = hv;
        }
        bf16x8 a0 = *(const bf16x8*)&hb[w][nl * WS + q * 8];
        bf16x8 a1 = *(const bf16x8*)&hb[w][nl * WS + 32 + q * 8];
        f32x4 a2[2];
        #pragma unroll
        for (int nb = 0; nb < 2; nb++) {
            a2[nb] = (f32x4){b2v[nb], b2v[nb], b2v[nb], b2v[nb]};
            a2[nb] = __builtin_amdgcn_mfma_f32_16x16x32_bf16(a0, w2f[nb][0], a2[nb], 0, 0, 0);
            a2[nb] = __builtin_amdgcn_mfma_f32_16x16x32_bf16(a1, w2f[nb][1], a2[nb], 0, 0, 0);
        }
        #pragma unroll
        for (int r = 0; r < 4; r++)
            #pragma unroll
            for (int nb = 0; nb < 2; nb++)
                xbf[(size_t)(R + q * 4 + r) * OUT_DIM + nb * 16 + nl] = (bf16)a2[nb][r];
    }
}

// ---------------- Kernel B: edge MLP, 2 nodes/iter + hybrid gelu (LUT + VALU) ----------------
__global__ __launch_bounds__(256) void gnn_edge_kernel(
    const bf16*  __restrict__ xbf,
    const float* __restrict__ igrid, const float* __restrict__ ogrid,
    const int*   __restrict__ nbi,
    const float* __restrict__ Wk1, const float* __restrict__ bk1,
    const float* __restrict__ Wk2, const float* __restrict__ bk2,
    const float* __restrict__ Wk3, const float* __restrict__ bk3,
    const float* __restrict__ gma, const float* __restrict__ bta,
    float* __restrict__ out)
{
    __shared__ __align__(16) bf16 tile[8][16 * WS];   // 2 tiles per wave (22 KB)
    __shared__ __align__(16) bf16 gtab[GTAB_N];       // gelu LUT [-16,16)/128 (8 KB)

    const int tid = threadIdx.x, w = tid >> 6, lane = tid & 63;
    const int q = lane >> 4, nl = lane & 15;
    bf16* __restrict__ TA = tile[w * 2];
    bf16* __restrict__ TB = tile[w * 2 + 1];

    // ---- build gelu table (exact erf), once per block ----
    for (int i = tid; i < GTAB_N; i += 256) {
        float x = (float)i * 0.0078125f - 16.0f;
        gtab[i] = (bf16)(0.5f * x * (1.0f + erff(x * 0.70710678f)));
    }

    // ---- weight B-frags in registers ----
    bf16x8 w1f[4][2], w2f[4][2], w3f[2][2];
    #pragma unroll
    for (int nb = 0; nb < 4; nb++) {
        #pragma unroll
        for (int j = 0; j < 8; j++) {
            w1f[nb][0][j] = (bf16)Wk1[(4 + q * 8 + j) * KH + nb * 16 + nl];
            float v1 = 0.0f;
            if (j < 4 && q == 0) v1 = Wk1[j * KH + nb * 16 + nl];
            w1f[nb][1][j] = (bf16)v1;
        }
        #pragma unroll
        for (int c = 0; c < 2; c++)
            #pragma unroll
            for (int j = 0; j < 8; j++) {
                int k = c * 32 + q * 8 + j, kp = ((k & 3) << 4) | (k >> 2);
                w2f[nb][c][j] = (bf16)Wk2[kp * KH + nb * 16 + nl];
            }
    }
    #pragma unroll
    for (int nb = 0; nb < 2; nb++)
        #pragma unroll
        for (int c = 0; c < 2; c++)
            #pragma unroll
            for (int j = 0; j < 8; j++) {
                int k = c * 32 + q * 8 + j, kp = ((k & 3) << 4) | (k >> 2);
                w3f[nb][c][j] = (bf16)Wk3[kp * OUT_DIM + nb * 16 + nl];
            }

    float b1v[4], b2v[4], b3v[2];
    #pragma unroll
    for (int nb = 0; nb < 4; nb++) { b1v[nb] = bk1[nb * 16 + nl]; b2v[nb] = bk2[nb * 16 + nl]; }
    b3v[0] = bk3[nl]; b3v[1] = bk3[16 + nl];
    const float g0 = gma[nl], g1 = gma[16 + nl], be0 = bta[nl], be1 = bta[16 + nl];

    const int gw = blockIdx.x * 4 + w;
    const int e = lane >> 2, part = lane & 3;

    // zero both tiles fully once (cols 36..63 stay zero forever; 0..35 rewritten per task)
    {
        const bf16x8 zf = {(bf16)0.f,(bf16)0.f,(bf16)0.f,(bf16)0.f,(bf16)0.f,(bf16)0.f,(bf16)0.f,(bf16)0.f};
        for (int i = lane * 8; i < 16 * WS; i += 64 * 8) { *(bf16x8*)&TA[i] = zf; *(bf16x8*)&TB[i] = zf; }
    }
    __syncthreads();   // table ready (one-time barrier)

    // gelu lookup: idx = round(x*128) + 2048, clamped
    #define GLUT(x) gtab[(unsigned)fminf(fmaxf(fmaf((x), 128.0f, 2048.5f), 0.0f), 4095.0f)]

    // ---- prologue prefetch (pair 0) ----
    int tA = gw, tB = gw + NWAVES;
    int nA = nbi[(tA & (NN - 1)) * KKN + e];
    int nB = nbi[(tB & (NN - 1)) * KKN + e];
    uint4 fyA = ((const uint4*)(xbf + ((size_t)((tA >> 15) * NN + nA)) * OUT_DIM))[part];
    uint4 fyB = ((const uint4*)(xbf + ((size_t)((tB >> 15) * NN + nB)) * OUT_DIM))[part];
    float2 ipA, opA, ipB, opB;
    if (part == 0) {
        ipA = ((const float2*)igrid)[nA]; opA = ((const float2*)ogrid)[tA & (NN - 1)];
        ipB = ((const float2*)igrid)[nB]; opB = ((const float2*)ogrid)[tB & (NN - 1)];
    }
    bf16 xA0 = xbf[(size_t)tA * OUT_DIM + nl],      xA1 = xbf[(size_t)tA * OUT_DIM + 16 + nl];
    bf16 xB0 = xbf[(size_t)tB * OUT_DIM + nl],      xB1 = xbf[(size_t)tB * OUT_DIM + 16 + nl];

    #pragma unroll 1
    for (int it = 0; it < TOT / (2 * NWAVES); ++it) {
        // ---- commit prefetched gathers ----
        *(uint4*)&TA[e * WS + part * 8] = fyA;
        *(uint4*)&TB[e * WS + part * 8] = fyB;
        if (part == 0) {
            bf16x4 pA = {(bf16)ipA.x, (bf16)ipA.y, (bf16)opA.x, (bf16)opA.y};
            bf16x4 pB = {(bf16)ipB.x, (bf16)ipB.y, (bf16)opB.x, (bf16)opB.y};
            *(bf16x4*)&TA[e * WS + 32] = pA;
            *(bf16x4*)&TB[e * WS + 32] = pB;
        }
        const float rA0 = (float)xA0, rA1 = (float)xA1, rB0 = (float)xB0, rB1 = (float)xB1;

        // ---- next pair indices (wraparound, always valid) ----
        const int tA2 = (tA + 2 * NWAVES) & (TOT - 1);
        const int tB2 = tA2 + NWAVES;
        const int nA2 = nbi[(tA2 & (NN - 1)) * KKN + e];
        const int nB2 = nbi[(tB2 & (NN - 1)) * KKN + e];

        // ---- layer 1 (A and B interleaved) ----
        bf16x8 aA0 = *(const bf16x8*)&TA[nl * WS + q * 8];
        bf16x8 aA1 = *(const bf16x8*)&TA[nl * WS + 32 + q * 8];
        bf16x8 aB0 = *(const bf16x8*)&TB[nl * WS + q * 8];
        bf16x8 aB1 = *(const bf16x8*)&TB[nl * WS + 32 + q * 8];
        f32x4 cA[4], cB[4];
        #pragma unroll
        for (int nb = 0; nb < 4; nb++) {
            cA[nb] = (f32x4){b1v[nb], b1v[nb], b1v[nb], b1v[nb]};
            cB[nb] = (f32x4){b1v[nb], b1v[nb], b1v[nb], b1v[nb]};
        }
        #pragma unroll
        for (int nb = 0; nb < 4; nb++) {
            cA[nb] = __builtin_amdgcn_mfma_f32_16x16x32_bf16(aA0, w1f[nb][0], cA[nb], 0, 0, 0);
            cB[nb] = __builtin_amdgcn_mfma_f32_16x16x32_bf16(aB0, w1f[nb][0], cB[nb], 0, 0, 0);
            cA[nb] = __builtin_amdgcn_mfma_f32_16x16x32_bf16(aA1, w1f[nb][1], cA[nb], 0, 0, 0);
            cB[nb] = __builtin_amdgcn_mfma_f32_16x16x32_bf16(aB1, w1f[nb][1], cB[nb], 0, 0, 0);
        }
        // hybrid gelu: nb 0-1 via LDS LUT, nb 2-3 via VALU (pipe balancing)
        #pragma unroll
        for (int r = 0; r < 4; r++) {
            bf16x4 hA, hB;
            hA[0] = GLUT(cA[0][r]);          hB[0] = GLUT(cB[0][r]);
            hA[1] = GLUT(cA[1][r]);          hB[1] = GLUT(cB[1][r]);
            hA[2] = (bf16)gelu_f(cA[2][r]);  hB[2] = (bf16)gelu_f(cB[2][r]);
            hA[3] = (bf16)gelu_f(cA[3][r]);  hB[3] = (bf16)gelu_f(cB[3][r]);
            *(bf16x4*)&TA[(q * 4 + r) * WS + nl * 4] = hA;
            *(bf16x4*)&TB[(q * 4 + r) * WS + nl * 4] = hB;
        }

        // ---- issue next pair's gathers (overlap layers 2-3) ----
        uint4 fyA2 = ((const uint4*)(xbf + ((size_t)((tA2 >> 15) * NN + nA2)) * OUT_DIM))[part];
        uint4 fyB2 = ((const uint4*)(xbf + ((size_t)((tB2 >> 15) * NN + nB2)) * OUT_DIM))[part];
        float2 ipA2, opA2, ipB2, opB2;
        if (part == 0) {
            ipA2 = ((const float2*)igrid)[nA2]; opA2 = ((const float2*)ogrid)[tA2 & (NN - 1)];
            ipB2 = ((const float2*)igrid)[nB2]; opB2 = ((const float2*)ogrid)[tB2 & (NN - 1)];
        }
        bf16 xA0n = xbf[(size_t)tA2 * OUT_DIM + nl],  xA1n = xbf[(size_t)tA2 * OUT_DIM + 16 + nl];
        bf16 xB0n = xbf[(size_t)tB2 * OUT_DIM + nl],  xB1n = xbf[(size_t)tB2 * OUT_DIM + 16 + nl];

        // ---- layer 2 ----
        aA0 = *(const bf16x8*)&TA[nl * WS + q * 8];
        aA1 = *(const bf16x8*)&TA[nl * WS + 32 + q * 8];
        aB0 = *(const bf16x8*)&TB[nl * WS + q * 8];
        aB1 = *(const bf16x8*)&TB[nl * WS + 32 + q * 8];
        #pragma unroll
        for (int nb = 0; nb < 4; nb++) {
            cA[nb] = (f32x4){b2v[nb], b2v[nb], b2v[nb], b2v[nb]};
            cB[nb] = (f32x4){b2v[nb], b2v[nb], b2v[nb], b2v[nb]};
        }
        #pragma unroll
        for (int nb = 0; nb < 4; nb++) {
            cA[nb] = __builtin_amdgcn_mfma_f32_16x16x32_bf16(aA0, w2f[nb][0], cA[nb], 0, 0, 0);
            cB[nb] = __builtin_amdgcn_mfma_f32_16x16x32_bf16(aB0, w2f[nb][0], cB[nb], 0, 0, 0);
            cA[nb] = __builtin_amdgcn_mfma_f32_16x16x32_bf16(aA1, w2f[nb][1], cA[nb], 0, 0, 0);
            cB[nb] = __builtin_amdgcn_mfma_f32_16x16x32_bf16(aB1, w2f[nb][1], cB[nb], 0, 0, 0);
        }
        #pragma unroll
        for (int r = 0; r < 4; r++) {
            bf16x4 hA, hB;
            hA[0] = GLUT(cA[0][r]);          hB[0] = GLUT(cB[0][r]);
            hA[1] = GLUT(cA[1][r]);          hB[1] = GLUT(cB[1][r]);
            hA[2] = (bf16)gelu_f(cA[2][r]);  hB[2] = (bf16)gelu_f(cB[2][r]);
            hA[3] = (bf16)gelu_f(cA[3][r]);  hB[3] = (bf16)gelu_f(cB[3][r]);
            *(bf16x4*)&TA[(q * 4 + r) * WS + nl * 4] = hA;
            *(bf16x4*)&TB[(q * 4 + r) * WS + nl * 4] = hB;
        }

        // ---- layer 3 ----
        aA0 = *(const bf16x8*)&TA[nl * WS + q * 8];
        aA1 = *(const bf16x8*)&TA[nl * WS + 32 + q * 8];
        aB0 = *(const bf16x8*)&TB[nl * WS + q * 8];
        aB1 = *(const bf16x8*)&TB[nl * WS + 32 + q * 8];
        f32x4 dA[2], dB[2];
        #pragma unroll
        for (int nb = 0; nb < 2; nb++) {
            dA[nb] = (f32x4){0.f, 0.f, 0.f, 0.f};
            dB[nb] = (f32x4){0.f, 0.f, 0.f, 0.f};
            dA[nb] = __builtin_amdgcn_mfma_f32_16x16x32_bf16(aA0, w3f[nb][0], dA[nb], 0, 0, 0);
            dB[nb] = __builtin_amdgcn_mfma_f32_16x16x32_bf16(aB0, w3f[nb][0], dB[nb], 0, 0, 0);
            dA[nb] = __builtin_amdgcn_mfma_f32_16x16x32_bf16(aA1, w3f[nb][1], dA[nb], 0, 0, 0);
            dB[nb] = __builtin_amdgcn_mfma_f32_16x16x32_bf16(aB1, w3f[nb][1], dB[nb], 0, 0, 0);
        }

        // ---- epilogues: mean over 16 edges + bias + residual, LN over 32 (DPP row sums) ----
        {
            float s0 = dA[0][0] + dA[0][1] + dA[0][2] + dA[0][3];
            float s1 = dA[1][0] + dA[1][1] + dA[1][2] + dA[1][3];
            float u0 = dB[0][0] + dB[0][1] + dB[0][2] + dB[0][3];
            float u1 = dB[1][0] + dB[1][1] + dB[1][2] + dB[1][3];
            s0 += __shfl_xor(s0, 16, 64); s0 += __shfl_xor(s0, 32, 64);
            s1 += __shfl_xor(s1, 16, 64); s1 += __shfl_xor(s1, 32, 64);
            u0 += __shfl_xor(u0, 16, 64); u0 += __shfl_xor(u0, 32, 64);
            u1 += __shfl_xor(u1, 16, 64); u1 += __shfl_xor(u1, 32, 64);

            float oA0 = s0 * 0.0625f + b3v[0] + rA0;
            float oA1 = s1 * 0.0625f + b3v[1] + rA1;
            float oB0 = u0 * 0.0625f + b3v[0] + rB0;
            float oB1 = u1 * 0.0625f + b3v[1] + rB1;

            float mA = rowsum16(oA0 + oA1) * (1.0f / 32.0f);
            float mB = rowsum16(oB0 + oB1) * (1.0f / 32.0f);
            float dA0 = oA0 - mA, dA1 = oA1 - mA, dB0 = oB0 - mB, dB1 = oB1 - mB;
            float vA = rowsum16(dA0 * dA0 + dA1 * dA1) * (1.0f / 32.0f);
            float vB = rowsum16(dB0 * dB0 + dB1 * dB1) * (1.0f / 32.0f);
            float rsA = rsqrtf(vA + 1e-5f);
            float rsB = rsqrtf(vB + 1e-5f);

            if (q == 0) {
                float* oa = out + (size_t)tA * OUT_DIM;
                float* ob = out + (size_t)tB * OUT_DIM;
                oa[nl]      = fmaf(dA0 * rsA, g0, be0);
                oa[16 + nl] = fmaf(dA1 * rsA, g1, be1);
                ob[nl]      = fmaf(dB0 * rsB, g0, be0);
                ob[16 + nl] = fmaf(dB1 * rsB, g1, be1);
            }
        }

        // ---- rotate prefetch state ----
        tA = tA2; tB = tB2;
        fyA = fyA2; fyB = fyB2;
        ipA = ipA2; opA = opA2; ipB = ipB2; opB = opB2;
        xA0 = xA0n; xA1 = xA1n; xB0 = xB0n; xB1 = xB1n;
    }
    #undef GLUT
}

extern "C" void kernel_launch(void* const* d_in, const int* in_sizes, int n_in,
                              void* d_out, int out_size, void* d_ws, size_t ws_size,
                              hipStream_t stream) {
    const float* inp   = (const float*)d_in[0];
    const float* igrid = (const float*)d_in[1];
    const float* ogrid = (const float*)d_in[2];
    const int*   nbi   = (const int*)d_in[3];
    const float* Wp1   = (const float*)d_in[4];
    const float* bp1   = (const float*)d_in[5];
    const float* Wp2   = (const float*)d_in[6];
    const float* bp2   = (const float*)d_in[7];
    const float* Wk1   = (const float*)d_in[8];
    const float* bk1   = (const float*)d_in[9];
    const float* Wk2   = (const float*)d_in[10];
    const float* bk2   = (const float*)d_in[11];
    const float* Wk3   = (const float*)d_in[12];
    const float* bk3   = (const float*)d_in[13];
    const float* gma   = (const float*)d_in[14];
    const float* bta   = (const float*)d_in[15];
    float* out = (float*)d_out;
    bf16* xbf = (bf16*)d_ws;   // B*N*32 bf16 = 8 MB

    point_mlp_kernel<<<1024, 256, 0, stream>>>(inp, Wp1, bp1, Wp2, bp2, xbf);
    gnn_edge_kernel<<<2048, 256, 0, stream>>>(xbf, igrid, ogrid, nbi,
                                              Wk1, bk1, Wk2, bk2, Wk3, bk3,
                                              gma, bta, out);
}